// Round 12
// baseline (327.628 us; speedup 1.0000x reference)
//
#include <hip/hip_runtime.h>
#include <hip/hip_bf16.h>
#include <math.h>

#define D 128
#define EPS 1e-5f
#define CAP 48        // fixed colA capacity per node (max deg of Poisson(16) data ~40)
#define OVCAP 65536   // overflow side-list capacity (pairs)

typedef unsigned short u16;
typedef short bf16x8 __attribute__((ext_vector_type(8)));
typedef float f32x4 __attribute__((ext_vector_type(4)));

static __device__ __forceinline__ u16 f2b(float f) {
    union { float f; unsigned u; } x{f};
    unsigned u = x.u;
    return (u16)((u + 0x7FFFu + ((u >> 16) & 1u)) >> 16);   // RNE
}
static __device__ __forceinline__ float bf2f(unsigned ubits) {
    union { unsigned u; float f; } x{ubits << 16};
    return x.f;
}
// packed-bf16 lane extract: low half = bits<<16, high half = bits&0xffff0000
static __device__ __forceinline__ float blo(unsigned u) {
    union { unsigned u; float f; } c{u << 16}; return c.f;
}
static __device__ __forceinline__ float bhi(unsigned u) {
    union { unsigned u; float f; } c{u & 0xffff0000u}; return c.f;
}

// async global->LDS, 16B per lane. LDS dest = wave-uniform base + lane*16.
static __device__ __forceinline__ void glds16(const u16* g, u16* l) {
#if __has_builtin(__builtin_amdgcn_global_load_lds)
    __builtin_amdgcn_global_load_lds(
        (const __attribute__((address_space(1))) unsigned int*)g,
        (__attribute__((address_space(3))) unsigned int*)l, 16, 0, 0);
#else
    int lane = threadIdx.x & 63;
    *(uint4*)(l + lane * 8) = *(const uint4*)g;
#endif
}

// ---------------- fused setup: wprep (blocks 0..111) + flat work (blocks 112+):
// cvt x->bf16 (+zero pad rows), bias concat, stats+b1p zero.
// wt layout: Wqkvs[512][128]@0 | WO[128][128]@65536 | W2[128][256]@81920 | W1'[256][128]@114688

__global__ __launch_bounds__(256) void setup_kernel(
    const float* __restrict__ x, u16* __restrict__ x16,
    const float* __restrict__ bq, const float* __restrict__ bk,
    const float* __restrict__ bv, const float* __restrict__ bs,
    float* __restrict__ bqkvs, float* __restrict__ stats, float* __restrict__ b1p,
    const float* __restrict__ Wq, const float* __restrict__ Wk,
    const float* __restrict__ Wv, const float* __restrict__ Ws,
    const float* __restrict__ WO, const float* __restrict__ W2,
    u16* __restrict__ wt,
    int n4, int n4p)
{
    __shared__ u16 t[32][33];
    int tid = threadIdx.x;
    if (blockIdx.x < 112) {
        // ---- weight transpose branch (f32 -> bf16 BT) ----
        int b = blockIdx.x;
        const float* src; u16* dst; int K, Nout;
        if (b < 64)      { int w = b >> 4; b &= 15; K = 128; Nout = 128;
                           src = (w == 0) ? Wq : (w == 1) ? Wk : (w == 2) ? Wv : Ws;
                           dst = wt + w * 16384; }
        else if (b < 80) { b -= 64; K = 128; Nout = 128; src = WO; dst = wt + 65536; }
        else             { b -= 80; K = 256; Nout = 128; src = W2; dst = wt + 81920; }
        int nx = Nout >> 5;
        int bx = (b % nx) * 32, by = (b / nx) * 32;
        int tx = tid & 31, ty = tid >> 5;
        #pragma unroll
        for (int r = 0; r < 32; r += 8)
            t[ty + r][tx] = f2b(src[(size_t)(by + ty + r) * Nout + bx + tx]);
        __syncthreads();
        #pragma unroll
        for (int r = 0; r < 32; r += 8)
            dst[(size_t)(bx + ty + r) * K + by + tx] = t[tx][ty + r];
        return;
    }
    // ---- flat branch ----
    long total = (long)n4p + 512 + 512 + 256;
    long stride = (long)(gridDim.x - 112) * 256;
    for (long i = (blockIdx.x - 112) * 256L + tid; i < total; i += stride) {
        if (i < n4p) {
            uint2 pk = make_uint2(0u, 0u);
            if (i < n4) {
                float4 v = ((const float4*)x)[i];
                pk.x = (unsigned)f2b(v.x) | ((unsigned)f2b(v.y) << 16);
                pk.y = (unsigned)f2b(v.z) | ((unsigned)f2b(v.w) << 16);
            }
            ((uint2*)x16)[i] = pk;
        } else if (i < (long)n4p + 512) {
            int c = (int)(i - n4p);
            float b = (c < 128) ? bq[c] : (c < 256) ? bk[c - 128]
                     : (c < 384) ? bv[c - 256] : bs[c - 384];
            bqkvs[c] = b;
        } else if (i < (long)n4p + 512 + 512) {
            stats[i - n4p - 512] = 0.f;
        } else {
            b1p[i - n4p - 1024] = 0.f;
        }
    }
}

// ---------------- prep1 (parallel, 8 blocks x 16-k slice): BN1 coeffs + ---------
// fold into W1' (bf16 BT) + b1' via atomicAdd into zeroed b1p.

__global__ void prep1_kernel(const float* __restrict__ stats,
                             const float* __restrict__ g1, const float* __restrict__ be1,
                             const float* __restrict__ W1, const float* __restrict__ b1,
                             float* __restrict__ ab1, u16* __restrict__ w1t,
                             float* __restrict__ b1p, float invN)
{
    __shared__ float a_sh[128], c_sh[128];
    int t = threadIdx.x;   // 256
    if (t < 128) {
        float mean = stats[t] * invN;
        float var = stats[128 + t] * invN - mean * mean;
        float a = g1[t] * rsqrtf(var + EPS);
        float c = be1[t] - a * mean;
        a_sh[t] = a; c_sh[t] = c;
        if (blockIdx.x == 0) { ab1[t] = a; ab1[128 + t] = c; }
    }
    __syncthreads();
    int k0 = blockIdx.x * 16;
    float acc = (blockIdx.x == 0) ? b1[t] : 0.f;
    for (int k = k0; k < k0 + 16; ++k) {
        float w = W1[(size_t)k * 256 + t];
        w1t[(size_t)t * 128 + k] = f2b(w * a_sh[k]);
        acc += c_sh[k] * w;
    }
    atomicAdd(&b1p[t], acc);
}

// ---------------- bf16 MFMA GEMM (r6-proven 128x128 structure) ------------------
// RES: 0 none, 1 fp32, 2 bf16, 3 bf16-with-bn(a,c in abp).
// FILL: QKVS launch carries a 5th grid-y slice doing the edge fill.
// r11->r12: colA/ov scatters are NON-TEMPORAL stores (r11 PMC: 48MB of write
// traffic for 3.2MB of colA data = 64B-line write-allocate amplification on
// the random scatter; nt bypasses L2 allocate, memory controller uses byte
// enables). ei reads nt too (one-shot stream, don't evict GEMM working set).

#define GBM 128
#define GBK 64
#define LDW 132

template<int RES, bool OUT16, bool STATS, bool RELU, bool FILL>
__global__ __launch_bounds__(256) void gemm_k(
    const u16* __restrict__ A, const u16* __restrict__ BT,
    const float* __restrict__ bias,
    const void* __restrict__ res, int ldres,
    const float* __restrict__ abp,
    void* __restrict__ Cout, int ldc,
    float* __restrict__ stats, int M, int K,
    const int* __restrict__ fei, int* __restrict__ fcur, int* __restrict__ fcolA,
    int* __restrict__ fovcnt, int* __restrict__ fov, int fE)
{
    __shared__ float smem[64 * LDW];             // 33792 B, unioned: K-loop tiles + epilogue
    __shared__ float stbuf[4][16][16];           // 4096 B, cross-wave stats staging
    u16* As = (u16*)smem;                        // [128][64] bf16 = 16 KB
    u16* Bs = As + GBM * GBK;                    // 16 KB

    int tid = threadIdx.x;

    if constexpr (FILL) {
        if (blockIdx.y == 4) {
            // ---- edge-fill slice: 8 strided edges/thread, batched atomics,
            //      non-temporal scatter ----
            int t = blockIdx.x * 256 + tid;
            int fstride = gridDim.x * 256;       // 100096 for gm=391
            int s8[8], d8[8], r8[8];
            bool ok[8];
            #pragma unroll
            for (int u = 0; u < 8; ++u) {
                int e = t + u * fstride;
                ok[u] = (e < fE);
                int ee = ok[u] ? e : 0;
                s8[u] = __builtin_nontemporal_load(&fei[ee]);
                d8[u] = __builtin_nontemporal_load(&fei[fE + ee]);
            }
            #pragma unroll
            for (int u = 0; u < 8; ++u)
                if (ok[u]) r8[u] = atomicAdd(&fcur[d8[u]], 1);
            #pragma unroll
            for (int u = 0; u < 8; ++u) {
                if (ok[u]) {
                    if (r8[u] < CAP) {
                        __builtin_nontemporal_store(s8[u], &fcolA[d8[u] * CAP + r8[u]]);
                    } else {
                        int o = atomicAdd(fovcnt, 1);
                        if (o < OVCAP) {
                            __builtin_nontemporal_store(d8[u], &fov[2 * o]);
                            __builtin_nontemporal_store(s8[u], &fov[2 * o + 1]);
                        }
                    }
                }
            }
            return;
        }
    }

    int wave = tid >> 6;
    int lane = tid & 63;
    int wm = (wave >> 1) * 64;
    int wn = (wave & 1) * 64;
    int bm = blockIdx.x * GBM;
    int bn = blockIdx.y * GBM;
    int lrow = lane & 15;
    int lquad = lane >> 4;

    int lrow8 = lane >> 3;                 // 0..7
    int ch = (lane & 7) ^ lrow8;           // xor-swizzled global chunk
    const u16* Ag = A + (size_t)(bm + wave * 32 + lrow8) * K + ch * 8;
    const u16* Bg = BT + (size_t)(bn + wave * 32 + lrow8) * K + ch * 8;
    u16* Al = As + wave * 32 * GBK;        // wave-uniform LDS bases
    u16* Bl = Bs + wave * 32 * GBK;

    f32x4 acc[4][4];
    #pragma unroll
    for (int i = 0; i < 4; ++i)
        #pragma unroll
        for (int j = 0; j < 4; ++j)
            acc[i][j] = (f32x4)0.f;

    for (int kc = 0; kc < K; kc += GBK) {
        #pragma unroll
        for (int t = 0; t < 4; ++t) {
            glds16(Ag + (size_t)(t * 8) * K + kc, Al + t * 8 * GBK);
            glds16(Bg + (size_t)(t * 8) * K + kc, Bl + t * 8 * GBK);
        }
        __syncthreads();
        #pragma unroll
        for (int ks = 0; ks < 2; ++ks) {
            int cfr = ((ks * 4 + lquad) ^ (lrow & 7)) * 8;
            bf16x8 af[4], bfr[4];
            #pragma unroll
            for (int i = 0; i < 4; ++i)
                af[i] = *(const bf16x8*)&As[(wm + i * 16 + lrow) * GBK + cfr];
            #pragma unroll
            for (int j = 0; j < 4; ++j)
                bfr[j] = *(const bf16x8*)&Bs[(wn + j * 16 + lrow) * GBK + cfr];
            // swapped operands: lane holds row = ...+lrow, cols = ...+lquad*4+r
            #pragma unroll
            for (int i = 0; i < 4; ++i)
                #pragma unroll
                for (int j = 0; j < 4; ++j)
                    acc[i][j] = __builtin_amdgcn_mfma_f32_16x16x32_bf16(bfr[j], af[i], acc[i][j], 0, 0, 0);
        }
        __syncthreads();
    }

    // ---- 2-pass epilogue: stage 64 rows, coalesced writeout ----
    int colg = (tid & 15) * 8;
    int gcol = bn + colg;
    float4 bs0 = *(const float4*)&bias[gcol];
    float4 bs1 = *(const float4*)&bias[gcol + 4];
    float bs8[8] = {bs0.x, bs0.y, bs0.z, bs0.w, bs1.x, bs1.y, bs1.z, bs1.w};

    float ss[8], sq[8];
    if constexpr (STATS) {
        #pragma unroll
        for (int r = 0; r < 8; ++r) { ss[r] = 0.f; sq[r] = 0.f; }
    }

    #pragma unroll
    for (int p = 0; p < 2; ++p) {
        if ((wave >> 1) == p) {
            #pragma unroll
            for (int i = 0; i < 4; ++i)
                #pragma unroll
                for (int j = 0; j < 4; ++j) {
                    int off = (i * 16 + lrow) * LDW + wn + j * 16 + lquad * 4;
                    *(float2*)&smem[off]     = make_float2(acc[i][j][0], acc[i][j][1]);
                    *(float2*)&smem[off + 2] = make_float2(acc[i][j][2], acc[i][j][3]);
                }
        }
        __syncthreads();
        #pragma unroll
        for (int it = 0; it < 4; ++it) {
            int rl = it * 16 + (tid >> 4);
            int grow = bm + p * 64 + rl;
            if (grow < M) {
                float o[8];
                float2 a0 = *(const float2*)&smem[rl * LDW + colg];
                float2 a1 = *(const float2*)&smem[rl * LDW + colg + 2];
                float2 a2 = *(const float2*)&smem[rl * LDW + colg + 4];
                float2 a3 = *(const float2*)&smem[rl * LDW + colg + 6];
                o[0] = a0.x + bs8[0]; o[1] = a0.y + bs8[1];
                o[2] = a1.x + bs8[2]; o[3] = a1.y + bs8[3];
                o[4] = a2.x + bs8[4]; o[5] = a2.y + bs8[5];
                o[6] = a3.x + bs8[6]; o[7] = a3.y + bs8[7];
                if constexpr (RES == 1) {
                    const float* rp = (const float*)res + (size_t)grow * ldres + gcol;
                    float4 r0 = *(const float4*)rp;
                    float4 r1 = *(const float4*)(rp + 4);
                    o[0] += r0.x; o[1] += r0.y; o[2] += r0.z; o[3] += r0.w;
                    o[4] += r1.x; o[5] += r1.y; o[6] += r1.z; o[7] += r1.w;
                }
                if constexpr (RES == 2) {
                    const u16* rp = (const u16*)res + (size_t)grow * ldres + gcol;
                    uint4 rv = *(const uint4*)rp;
                    o[0] += bf2f(rv.x & 0xffffu); o[1] += bf2f(rv.x >> 16);
                    o[2] += bf2f(rv.y & 0xffffu); o[3] += bf2f(rv.y >> 16);
                    o[4] += bf2f(rv.z & 0xffffu); o[5] += bf2f(rv.z >> 16);
                    o[6] += bf2f(rv.w & 0xffffu); o[7] += bf2f(rv.w >> 16);
                }
                if constexpr (RES == 3) {
                    const u16* rp = (const u16*)res + (size_t)grow * ldres + gcol;
                    uint4 rv = *(const uint4*)rp;
                    float hv[8] = {
                        bf2f(rv.x & 0xffffu), bf2f(rv.x >> 16),
                        bf2f(rv.y & 0xffffu), bf2f(rv.y >> 16),
                        bf2f(rv.z & 0xffffu), bf2f(rv.z >> 16),
                        bf2f(rv.w & 0xffffu), bf2f(rv.w >> 16)};
                    #pragma unroll
                    for (int q = 0; q < 2; ++q) {
                        float4 av = *(const float4*)&abp[gcol + q * 4];
                        float4 cv = *(const float4*)&abp[128 + gcol + q * 4];
                        o[q * 4]     += av.x * hv[q * 4]     + cv.x;
                        o[q * 4 + 1] += av.y * hv[q * 4 + 1] + cv.y;
                        o[q * 4 + 2] += av.z * hv[q * 4 + 2] + cv.z;
                        o[q * 4 + 3] += av.w * hv[q * 4 + 3] + cv.w;
                    }
                }
                if constexpr (RELU) {
                    #pragma unroll
                    for (int r = 0; r < 8; ++r) o[r] = fmaxf(o[r], 0.f);
                }
                if constexpr (STATS) {
                    #pragma unroll
                    for (int r = 0; r < 8; ++r) { ss[r] += o[r]; sq[r] += o[r] * o[r]; }
                }
                if constexpr (OUT16) {
                    uint4 pk;
                    pk.x = (unsigned)f2b(o[0]) | ((unsigned)f2b(o[1]) << 16);
                    pk.y = (unsigned)f2b(o[2]) | ((unsigned)f2b(o[3]) << 16);
                    pk.z = (unsigned)f2b(o[4]) | ((unsigned)f2b(o[5]) << 16);
                    pk.w = (unsigned)f2b(o[6]) | ((unsigned)f2b(o[7]) << 16);
                    *(uint4*)&((u16*)Cout)[(size_t)grow * ldc + gcol] = pk;
                } else {
                    float* cp = (float*)Cout + (size_t)grow * ldc + gcol;
                    *(float4*)cp = make_float4(o[0], o[1], o[2], o[3]);
                    *(float4*)(cp + 4) = make_float4(o[4], o[5], o[6], o[7]);
                }
            }
        }
        __syncthreads();
    }

    if constexpr (STATS) {
        #pragma unroll
        for (int r = 0; r < 8; ++r) {
            ss[r] += __shfl_xor(ss[r], 16); ss[r] += __shfl_xor(ss[r], 32);
            sq[r] += __shfl_xor(sq[r], 16); sq[r] += __shfl_xor(sq[r], 32);
        }
        if (lane < 16) {
            #pragma unroll
            for (int r = 0; r < 8; ++r) {
                stbuf[wave][lane][r] = ss[r];
                stbuf[wave][lane][8 + r] = sq[r];
            }
        }
        __syncthreads();
        int c16 = tid >> 4, r = tid & 15;
        float v = stbuf[0][c16][r] + stbuf[1][c16][r] + stbuf[2][c16][r] + stbuf[3][c16][r];
        int col = bn + c16 * 8 + (r & 7);
        atomicAdd(&stats[(r < 8 ? 0 : 128) + col], v);
    }
}

// ---------------- attention: 16-lane group per dst node (r1-proven structure) ----
// Fixed-capacity rows: beg = n*CAP, deg = cur[n]; overflow side-list handled at
// the end (empty in practice). No running max (|score| <~ 3 => exp safe in fp32).
// qkvs row layout: [q(128)|k(128)|v(128)|t_init(128)] bf16, stride 512 (1024 B).

__global__ __launch_bounds__(256) void attn_kernel(
    const u16* __restrict__ qkvs, const int* __restrict__ deg_arr,
    const int* __restrict__ colA, const int* __restrict__ ovcnt,
    const int* __restrict__ ov, u16* __restrict__ t16, int Nn)
{
    int tid = threadIdx.x;
    int gid = tid >> 4;              // group in block, 0..15
    int gl = tid & 15;               // lane in group
    int n = blockIdx.x * 16 + gid;
    if (n >= Nn) return;

    int deg = deg_arr[n];
    int beg = n * CAP;
    int end = beg + (deg < CAP ? deg : CAP);
    const char* base = (const char*)qkvs;
    const u16* qr = qkvs + (size_t)n * 512;
    uint4 qu = *(const uint4*)(qr + gl * 8);
    float q[8] = { blo(qu.x), bhi(qu.x), blo(qu.y), bhi(qu.y),
                   blo(qu.z), bhi(qu.z), blo(qu.w), bhi(qu.w) };

    const float scale = 0.08838834764831845f;   // 1/sqrt(128)
    float l = 0.f;
    float a[8] = {0.f, 0.f, 0.f, 0.f, 0.f, 0.f, 0.f, 0.f};
    unsigned lbyte = (unsigned)gl * 16u;        // byte offset within 256B chunk

#define ATTN_DOT(kk_, d_)                                              \
    {                                                                  \
        d_  = q[0] * blo(kk_.x); d_ = fmaf(q[1], bhi(kk_.x), d_);      \
        d_ = fmaf(q[2], blo(kk_.y), d_); d_ = fmaf(q[3], bhi(kk_.y), d_);\
        d_ = fmaf(q[4], blo(kk_.z), d_); d_ = fmaf(q[5], bhi(kk_.z), d_);\
        d_ = fmaf(q[6], blo(kk_.w), d_); d_ = fmaf(q[7], bhi(kk_.w), d_);\
    }
#define ATTN_UPD(dd_, vv_)                                             \
    {                                                                  \
        float d_ = dd_;                                                \
        d_ += __shfl_xor(d_, 1); d_ += __shfl_xor(d_, 2);              \
        d_ += __shfl_xor(d_, 4); d_ += __shfl_xor(d_, 8);              \
        float p_ = __expf(d_ * scale);                                 \
        l += p_;                                                       \
        a[0] = fmaf(p_, blo(vv_.x), a[0]); a[1] = fmaf(p_, bhi(vv_.x), a[1]);\
        a[2] = fmaf(p_, blo(vv_.y), a[2]); a[3] = fmaf(p_, bhi(vv_.y), a[3]);\
        a[4] = fmaf(p_, blo(vv_.z), a[4]); a[5] = fmaf(p_, bhi(vv_.z), a[5]);\
        a[6] = fmaf(p_, blo(vv_.w), a[6]); a[7] = fmaf(p_, bhi(vv_.w), a[7]);\
    }

    int i = beg;
    for (; i + 8 <= end; i += 8) {
        uint4 kk[8], vv[8];
        #pragma unroll
        for (int u = 0; u < 8; ++u) {
            unsigned off = ((unsigned)colA[i + u] << 10) + lbyte;
            kk[u] = *(const uint4*)(base + off + 256);
            vv[u] = *(const uint4*)(base + off + 512);
        }
        #pragma unroll
        for (int u = 0; u < 8; ++u) {
            float d; ATTN_DOT(kk[u], d);
            ATTN_UPD(d, vv[u]);
        }
    }
    for (; i + 4 <= end; i += 4) {
        uint4 kk[4], vv[4];
        #pragma unroll
        for (int u = 0; u < 4; ++u) {
            unsigned off = ((unsigned)colA[i + u] << 10) + lbyte;
            kk[u] = *(const uint4*)(base + off + 256);
            vv[u] = *(const uint4*)(base + off + 512);
        }
        #pragma unroll
        for (int u = 0; u < 4; ++u) {
            float d; ATTN_DOT(kk[u], d);
            ATTN_UPD(d, vv[u]);
        }
    }
    for (; i < end; ++i) {
        unsigned off = ((unsigned)colA[i] << 10) + lbyte;
        uint4 kk = *(const uint4*)(base + off + 256);
        uint4 vv = *(const uint4*)(base + off + 512);
        float d; ATTN_DOT(kk, d);
        ATTN_UPD(d, vv);
    }
    // overflow edges (deg > CAP); empty for this data, correctness path only
    int ovn = *ovcnt;
    if (ovn > 0) {
        if (ovn > OVCAP) ovn = OVCAP;
        for (int j = 0; j < ovn; ++j) {
            if (ov[2 * j] == n) {
                unsigned off = ((unsigned)ov[2 * j + 1] << 10) + lbyte;
                uint4 kk = *(const uint4*)(base + off + 256);
                uint4 vv = *(const uint4*)(base + off + 512);
                float d; ATTN_DOT(kk, d);
                ATTN_UPD(d, vv);
            }
        }
    }
#undef ATTN_DOT
#undef ATTN_UPD

    uint4 tu = *(const uint4*)(qr + 384 + gl * 8);
    float t[8] = { blo(tu.x), bhi(tu.x), blo(tu.y), bhi(tu.y),
                   blo(tu.z), bhi(tu.z), blo(tu.w), bhi(tu.w) };
    if (l > 0.f) {
        float inv = 1.f / l;
        #pragma unroll
        for (int c = 0; c < 8; ++c) t[c] = fmaf(a[c], inv, t[c]);
    }
    uint4 pk;
    pk.x = (unsigned)f2b(t[0]) | ((unsigned)f2b(t[1]) << 16);
    pk.y = (unsigned)f2b(t[2]) | ((unsigned)f2b(t[3]) << 16);
    pk.z = (unsigned)f2b(t[4]) | ((unsigned)f2b(t[5]) << 16);
    pk.w = (unsigned)f2b(t[6]) | ((unsigned)f2b(t[7]) << 16);
    *(uint4*)&t16[(size_t)n * 128 + gl * 8] = pk;
}

// ---------------- BN2 apply (prep fused; reads bf16 h2) ----------------
// Each thread handles 8 bf16 (uint4) -> writes 2x float4 (32B) coalesced.

__global__ __launch_bounds__(256) void bn_apply_kernel(
    const u16* __restrict__ h, const float* __restrict__ stats,
    const float* __restrict__ g, const float* __restrict__ be,
    float* __restrict__ out, int total8, float invN)
{
    __shared__ float ab[256];
    int tid = threadIdx.x;
    if (tid < 128) {
        float mean = stats[tid] * invN;
        float var = stats[128 + tid] * invN - mean * mean;
        float a = g[tid] * rsqrtf(var + EPS);
        ab[tid] = a;
        ab[128 + tid] = be[tid] - a * mean;
    }
    __syncthreads();
    int stride = gridDim.x * 256;
    for (int i8 = blockIdx.x * 256 + tid; i8 < total8; i8 += stride) {
        int cb = (i8 & 15) * 8;
        uint4 hv = ((const uint4*)h)[i8];
        float o[8] = { blo(hv.x), bhi(hv.x), blo(hv.y), bhi(hv.y),
                       blo(hv.z), bhi(hv.z), blo(hv.w), bhi(hv.w) };
        float* cp = out + (size_t)i8 * 8;
        *(float4*)cp = make_float4(
            ab[cb] * o[0] + ab[128 + cb],
            ab[cb + 1] * o[1] + ab[128 + cb + 1],
            ab[cb + 2] * o[2] + ab[128 + cb + 2],
            ab[cb + 3] * o[3] + ab[128 + cb + 3]);
        *(float4*)(cp + 4) = make_float4(
            ab[cb + 4] * o[4] + ab[128 + cb + 4],
            ab[cb + 5] * o[5] + ab[128 + cb + 5],
            ab[cb + 6] * o[6] + ab[128 + cb + 6],
            ab[cb + 7] * o[7] + ab[128 + cb + 7]);
    }
}

// ---------------- launch ----------------

extern "C" void kernel_launch(void* const* d_in, const int* in_sizes, int n_in,
                              void* d_out, int out_size, void* d_ws, size_t ws_size,
                              hipStream_t stream) {
    const float* x  = (const float*)d_in[0];
    const int*   ei = (const int*)d_in[1];
    const float* Wq = (const float*)d_in[2];  const float* bq = (const float*)d_in[3];
    const float* Wk = (const float*)d_in[4];  const float* bk = (const float*)d_in[5];
    const float* Wv = (const float*)d_in[6];  const float* bv = (const float*)d_in[7];
    const float* Ws = (const float*)d_in[8];  const float* bs = (const float*)d_in[9];
    const float* WO = (const float*)d_in[10]; const float* bO = (const float*)d_in[11];
    const float* W1 = (const float*)d_in[12]; const float* b1 = (const float*)d_in[13];
    const float* W2 = (const float*)d_in[14]; const float* b2 = (const float*)d_in[15];
    const float* g1 = (const float*)d_in[16]; const float* be1 = (const float*)d_in[17];
    const float* g2 = (const float*)d_in[18]; const float* be2 = (const float*)d_in[19];

    const int N = in_sizes[0] / D;            // 50000
    const int E = in_sizes[1] / 2;            // 800000
    float* out = (float*)d_out;

    int gm = (N + GBM - 1) / GBM;             // 391
    int Npad = gm * GBM;                      // 50048
    size_t NDp = (size_t)Npad * D;

    // ---- workspace (~88 MB) ----
    u16* buf0 = (u16*)d_ws;                   // [Npad][128]: x16 -> h16 (in-place at Oproj)
    u16* t16 = buf0 + NDp;                    // [Npad][128] attn output
    u16* qkvs = t16 + NDp;                    // [Npad][512]
    float* stats = (float*)(qkvs + (size_t)Npad * 512);  // 512 (BN1 | BN2)
    float* ab1 = stats + 512;                 // 256
    float* bqkvs = ab1 + 256;                 // 512
    float* b1p = bqkvs + 512;                 // 256
    u16* wt = (u16*)(b1p + 256);              // 147456: Wqkvs|WO|W2|W1'
    int* cur = (int*)(wt + 147456);           // N   (memset N+1 covers ovcnt)
    int* ovcnt = cur + N;                     // 1
    int* ov = ovcnt + 1;                      // 2*OVCAP
    int* colA = ov + 2 * OVCAP;               // CAP*N
    // aliases:
    u16* x16 = buf0;                          // pad rows zeroed by setup
    u16* h16 = buf0;                          // Oproj writes in-place (row-owned, RES=2 from x16)
    u16* zb16 = qkvs;                         // [Npad][256]; qkvs dead after attn
    u16* h2b = qkvs + (size_t)Npad * 256;     // [N][128] bf16 pre-BN2, disjoint from zb16

    // --- setup (x16 + biases + zeros + weight prep) ---
    hipMemsetAsync(cur, 0, (size_t)(N + 1) * sizeof(int), stream);
    setup_kernel<<<1136, 256, 0, stream>>>(x, x16, bq, bk, bv, bs, bqkvs, stats, b1p,
                                           Wq, Wk, Wv, Ws, WO, W2, wt,
                                           N * 32, Npad * 32);

    // --- QKVS GEMM (y=0..3) + edge-fill slice (y=4), overlapped in one dispatch ---
    gemm_k<0, true, false, false, true><<<dim3(gm, 5), 256, 0, stream>>>(
        x16, wt, bqkvs, nullptr, 0, nullptr, qkvs, 512, nullptr, Npad, 128,
        ei, cur, colA, ovcnt, ov, E);

    // --- attention: t16 = t_init + softmax-agg(v) ---
    attn_kernel<<<(N + 15) / 16, 256, 0, stream>>>(qkvs, cur, colA, ovcnt, ov, t16, N);

    // --- O-proj + residual1(bf16 x16) + BN1 stats: h16 = bf16(x16 + t16@WO + bO) ---
    gemm_k<2, true, true, false, false><<<dim3(gm, 1), 256, 0, stream>>>(
        t16, wt + 65536, bO, x16, 128, nullptr, h16, 128, stats, N, 128,
        nullptr, nullptr, nullptr, nullptr, nullptr, 0);

    // --- prep1 (parallel): ab1, W1' (bf16, BN1 folded), b1' ---
    prep1_kernel<<<8, 256, 0, stream>>>(stats, g1, be1, W1, b1, ab1, wt + 114688, b1p,
                                        1.f / (float)N);

    // --- FFN1: zb16 = relu(h16@W1' + b1'), all Npad rows (pads -> relu(b1'), defined) ---
    gemm_k<0, true, false, true, false><<<dim3(gm, 2), 256, 0, stream>>>(
        h16, wt + 114688, b1p, nullptr, 0, nullptr, zb16, 256, nullptr, Npad, 128,
        nullptr, nullptr, nullptr, nullptr, nullptr, 0);

    // --- FFN2 + residual2(bn1) + BN2 stats: h2b = bf16((a1*h16+c1) + zb16@W2 + b2) ---
    gemm_k<3, true, true, false, false><<<dim3(gm, 1), 256, 0, stream>>>(
        zb16, wt + 81920, b2, h16, 128, ab1, h2b, 128, stats + 256, N, 256,
        nullptr, nullptr, nullptr, nullptr, nullptr, 0);

    // --- BN2 apply (prep fused) -> out ---
    bn_apply_kernel<<<1024, 256, 0, stream>>>(h2b, stats + 256, g2, be2, out,
                                              N * 16, 1.f / (float)N);
}

// Round 13
// 298.201 us; speedup vs baseline: 1.0987x; 1.0987x over previous
//
#include <hip/hip_runtime.h>
#include <hip/hip_bf16.h>
#include <math.h>

#define D 128
#define EPS 1e-5f
#define CAP 48        // fixed colA capacity per node (max deg of Poisson(16) data ~40)
#define OVCAP 65536   // overflow side-list capacity (pairs)

typedef unsigned short u16;
typedef short bf16x8 __attribute__((ext_vector_type(8)));
typedef float f32x4 __attribute__((ext_vector_type(4)));

static __device__ __forceinline__ u16 f2b(float f) {
    union { float f; unsigned u; } x{f};
    unsigned u = x.u;
    return (u16)((u + 0x7FFFu + ((u >> 16) & 1u)) >> 16);   // RNE
}
static __device__ __forceinline__ float bf2f(unsigned ubits) {
    union { unsigned u; float f; } x{ubits << 16};
    return x.f;
}
// packed-bf16 lane extract: low half = bits<<16, high half = bits&0xffff0000
static __device__ __forceinline__ float blo(unsigned u) {
    union { unsigned u; float f; } c{u << 16}; return c.f;
}
static __device__ __forceinline__ float bhi(unsigned u) {
    union { unsigned u; float f; } c{u & 0xffff0000u}; return c.f;
}

// async global->LDS, 16B per lane. LDS dest = wave-uniform base + lane*16.
static __device__ __forceinline__ void glds16(const u16* g, u16* l) {
#if __has_builtin(__builtin_amdgcn_global_load_lds)
    __builtin_amdgcn_global_load_lds(
        (const __attribute__((address_space(1))) unsigned int*)g,
        (__attribute__((address_space(3))) unsigned int*)l, 16, 0, 0);
#else
    int lane = threadIdx.x & 63;
    *(uint4*)(l + lane * 8) = *(const uint4*)g;
#endif
}

// ---------------- fused setup: wprep (blocks 0..111) + flat work (blocks 112+):
// cvt x->bf16 (+zero pad rows), bias concat, stats+b1p zero.
// wt layout: Wqkvs[512][128]@0 | WO[128][128]@65536 | W2[128][256]@81920 | W1'[256][128]@114688

__global__ __launch_bounds__(256) void setup_kernel(
    const float* __restrict__ x, u16* __restrict__ x16,
    const float* __restrict__ bq, const float* __restrict__ bk,
    const float* __restrict__ bv, const float* __restrict__ bs,
    float* __restrict__ bqkvs, float* __restrict__ stats, float* __restrict__ b1p,
    const float* __restrict__ Wq, const float* __restrict__ Wk,
    const float* __restrict__ Wv, const float* __restrict__ Ws,
    const float* __restrict__ WO, const float* __restrict__ W2,
    u16* __restrict__ wt,
    int n4, int n4p)
{
    __shared__ u16 t[32][33];
    int tid = threadIdx.x;
    if (blockIdx.x < 112) {
        // ---- weight transpose branch (f32 -> bf16 BT) ----
        int b = blockIdx.x;
        const float* src; u16* dst; int K, Nout;
        if (b < 64)      { int w = b >> 4; b &= 15; K = 128; Nout = 128;
                           src = (w == 0) ? Wq : (w == 1) ? Wk : (w == 2) ? Wv : Ws;
                           dst = wt + w * 16384; }
        else if (b < 80) { b -= 64; K = 128; Nout = 128; src = WO; dst = wt + 65536; }
        else             { b -= 80; K = 256; Nout = 128; src = W2; dst = wt + 81920; }
        int nx = Nout >> 5;
        int bx = (b % nx) * 32, by = (b / nx) * 32;
        int tx = tid & 31, ty = tid >> 5;
        #pragma unroll
        for (int r = 0; r < 32; r += 8)
            t[ty + r][tx] = f2b(src[(size_t)(by + ty + r) * Nout + bx + tx]);
        __syncthreads();
        #pragma unroll
        for (int r = 0; r < 32; r += 8)
            dst[(size_t)(bx + ty + r) * K + by + tx] = t[tx][ty + r];
        return;
    }
    // ---- flat branch ----
    long total = (long)n4p + 512 + 512 + 256;
    long stride = (long)(gridDim.x - 112) * 256;
    for (long i = (blockIdx.x - 112) * 256L + tid; i < total; i += stride) {
        if (i < n4p) {
            uint2 pk = make_uint2(0u, 0u);
            if (i < n4) {
                float4 v = ((const float4*)x)[i];
                pk.x = (unsigned)f2b(v.x) | ((unsigned)f2b(v.y) << 16);
                pk.y = (unsigned)f2b(v.z) | ((unsigned)f2b(v.w) << 16);
            }
            ((uint2*)x16)[i] = pk;
        } else if (i < (long)n4p + 512) {
            int c = (int)(i - n4p);
            float b = (c < 128) ? bq[c] : (c < 256) ? bk[c - 128]
                     : (c < 384) ? bv[c - 256] : bs[c - 384];
            bqkvs[c] = b;
        } else if (i < (long)n4p + 512 + 512) {
            stats[i - n4p - 512] = 0.f;
        } else {
            b1p[i - n4p - 1024] = 0.f;
        }
    }
}

// ---------------- prep1 (parallel, 8 blocks x 16-k slice): BN1 coeffs + ---------
// fold into W1' (bf16 BT) + b1' via atomicAdd into zeroed b1p.

__global__ void prep1_kernel(const float* __restrict__ stats,
                             const float* __restrict__ g1, const float* __restrict__ be1,
                             const float* __restrict__ W1, const float* __restrict__ b1,
                             float* __restrict__ ab1, u16* __restrict__ w1t,
                             float* __restrict__ b1p, float invN)
{
    __shared__ float a_sh[128], c_sh[128];
    int t = threadIdx.x;   // 256
    if (t < 128) {
        float mean = stats[t] * invN;
        float var = stats[128 + t] * invN - mean * mean;
        float a = g1[t] * rsqrtf(var + EPS);
        float c = be1[t] - a * mean;
        a_sh[t] = a; c_sh[t] = c;
        if (blockIdx.x == 0) { ab1[t] = a; ab1[128 + t] = c; }
    }
    __syncthreads();
    int k0 = blockIdx.x * 16;
    float acc = (blockIdx.x == 0) ? b1[t] : 0.f;
    for (int k = k0; k < k0 + 16; ++k) {
        float w = W1[(size_t)k * 256 + t];
        w1t[(size_t)t * 128 + k] = f2b(w * a_sh[k]);
        acc += c_sh[k] * w;
    }
    atomicAdd(&b1p[t], acc);
}

// ---------------- bf16 MFMA GEMM (r6-proven 128x128 structure) ------------------
// RES: 0 none, 1 fp32, 2 bf16, 3 bf16-with-bn(a,c in abp).
// FILL: QKVS launch carries the edge-fill as slice y=0 (GEMM at y=1..4).
// r12->r13: nt stores REVERTED (write granularity is controller-side; nt was
// slower). Fill moved to y=0: blocks launch in linear-ID order, so a y=4 fill
// slice ran as a serialized TAIL after all GEMM blocks (r11: 78us ~= 38 GEMM +
// 40 fill). First slice => fill occupies CUs first, GEMM floods in behind =>
// true overlap.

#define GBM 128
#define GBK 64
#define LDW 132

template<int RES, bool OUT16, bool STATS, bool RELU, bool FILL>
__global__ __launch_bounds__(256) void gemm_k(
    const u16* __restrict__ A, const u16* __restrict__ BT,
    const float* __restrict__ bias,
    const void* __restrict__ res, int ldres,
    const float* __restrict__ abp,
    void* __restrict__ Cout, int ldc,
    float* __restrict__ stats, int M, int K,
    const int* __restrict__ fei, int* __restrict__ fcur, int* __restrict__ fcolA,
    int* __restrict__ fovcnt, int* __restrict__ fov, int fE)
{
    __shared__ float smem[64 * LDW];             // 33792 B, unioned: K-loop tiles + epilogue
    __shared__ float stbuf[4][16][16];           // 4096 B, cross-wave stats staging
    u16* As = (u16*)smem;                        // [128][64] bf16 = 16 KB
    u16* Bs = As + GBM * GBK;                    // 16 KB

    int tid = threadIdx.x;

    if constexpr (FILL) {
        if (blockIdx.y == 0) {
            // ---- edge-fill slice: 8 strided edges/thread, batched atomics ----
            int t = blockIdx.x * 256 + tid;
            int fstride = gridDim.x * 256;       // 100096 for gm=391
            int s8[8], d8[8], r8[8];
            bool ok[8];
            #pragma unroll
            for (int u = 0; u < 8; ++u) {
                int e = t + u * fstride;
                ok[u] = (e < fE);
                int ee = ok[u] ? e : 0;
                s8[u] = fei[ee];
                d8[u] = fei[fE + ee];
            }
            #pragma unroll
            for (int u = 0; u < 8; ++u)
                if (ok[u]) r8[u] = atomicAdd(&fcur[d8[u]], 1);
            #pragma unroll
            for (int u = 0; u < 8; ++u) {
                if (ok[u]) {
                    if (r8[u] < CAP) {
                        fcolA[d8[u] * CAP + r8[u]] = s8[u];
                    } else {
                        int o = atomicAdd(fovcnt, 1);
                        if (o < OVCAP) { fov[2 * o] = d8[u]; fov[2 * o + 1] = s8[u]; }
                    }
                }
            }
            return;
        }
    }

    int wave = tid >> 6;
    int lane = tid & 63;
    int wm = (wave >> 1) * 64;
    int wn = (wave & 1) * 64;
    int bm = blockIdx.x * GBM;
    int yg = FILL ? (blockIdx.y - 1) : blockIdx.y;
    int bn = yg * GBM;
    int lrow = lane & 15;
    int lquad = lane >> 4;

    int lrow8 = lane >> 3;                 // 0..7
    int ch = (lane & 7) ^ lrow8;           // xor-swizzled global chunk
    const u16* Ag = A + (size_t)(bm + wave * 32 + lrow8) * K + ch * 8;
    const u16* Bg = BT + (size_t)(bn + wave * 32 + lrow8) * K + ch * 8;
    u16* Al = As + wave * 32 * GBK;        // wave-uniform LDS bases
    u16* Bl = Bs + wave * 32 * GBK;

    f32x4 acc[4][4];
    #pragma unroll
    for (int i = 0; i < 4; ++i)
        #pragma unroll
        for (int j = 0; j < 4; ++j)
            acc[i][j] = (f32x4)0.f;

    for (int kc = 0; kc < K; kc += GBK) {
        #pragma unroll
        for (int t = 0; t < 4; ++t) {
            glds16(Ag + (size_t)(t * 8) * K + kc, Al + t * 8 * GBK);
            glds16(Bg + (size_t)(t * 8) * K + kc, Bl + t * 8 * GBK);
        }
        __syncthreads();
        #pragma unroll
        for (int ks = 0; ks < 2; ++ks) {
            int cfr = ((ks * 4 + lquad) ^ (lrow & 7)) * 8;
            bf16x8 af[4], bfr[4];
            #pragma unroll
            for (int i = 0; i < 4; ++i)
                af[i] = *(const bf16x8*)&As[(wm + i * 16 + lrow) * GBK + cfr];
            #pragma unroll
            for (int j = 0; j < 4; ++j)
                bfr[j] = *(const bf16x8*)&Bs[(wn + j * 16 + lrow) * GBK + cfr];
            // swapped operands: lane holds row = ...+lrow, cols = ...+lquad*4+r
            #pragma unroll
            for (int i = 0; i < 4; ++i)
                #pragma unroll
                for (int j = 0; j < 4; ++j)
                    acc[i][j] = __builtin_amdgcn_mfma_f32_16x16x32_bf16(bfr[j], af[i], acc[i][j], 0, 0, 0);
        }
        __syncthreads();
    }

    // ---- 2-pass epilogue: stage 64 rows, coalesced writeout ----
    int colg = (tid & 15) * 8;
    int gcol = bn + colg;
    float4 bs0 = *(const float4*)&bias[gcol];
    float4 bs1 = *(const float4*)&bias[gcol + 4];
    float bs8[8] = {bs0.x, bs0.y, bs0.z, bs0.w, bs1.x, bs1.y, bs1.z, bs1.w};

    float ss[8], sq[8];
    if constexpr (STATS) {
        #pragma unroll
        for (int r = 0; r < 8; ++r) { ss[r] = 0.f; sq[r] = 0.f; }
    }

    #pragma unroll
    for (int p = 0; p < 2; ++p) {
        if ((wave >> 1) == p) {
            #pragma unroll
            for (int i = 0; i < 4; ++i)
                #pragma unroll
                for (int j = 0; j < 4; ++j) {
                    int off = (i * 16 + lrow) * LDW + wn + j * 16 + lquad * 4;
                    *(float2*)&smem[off]     = make_float2(acc[i][j][0], acc[i][j][1]);
                    *(float2*)&smem[off + 2] = make_float2(acc[i][j][2], acc[i][j][3]);
                }
        }
        __syncthreads();
        #pragma unroll
        for (int it = 0; it < 4; ++it) {
            int rl = it * 16 + (tid >> 4);
            int grow = bm + p * 64 + rl;
            if (grow < M) {
                float o[8];
                float2 a0 = *(const float2*)&smem[rl * LDW + colg];
                float2 a1 = *(const float2*)&smem[rl * LDW + colg + 2];
                float2 a2 = *(const float2*)&smem[rl * LDW + colg + 4];
                float2 a3 = *(const float2*)&smem[rl * LDW + colg + 6];
                o[0] = a0.x + bs8[0]; o[1] = a0.y + bs8[1];
                o[2] = a1.x + bs8[2]; o[3] = a1.y + bs8[3];
                o[4] = a2.x + bs8[4]; o[5] = a2.y + bs8[5];
                o[6] = a3.x + bs8[6]; o[7] = a3.y + bs8[7];
                if constexpr (RES == 1) {
                    const float* rp = (const float*)res + (size_t)grow * ldres + gcol;
                    float4 r0 = *(const float4*)rp;
                    float4 r1 = *(const float4*)(rp + 4);
                    o[0] += r0.x; o[1] += r0.y; o[2] += r0.z; o[3] += r0.w;
                    o[4] += r1.x; o[5] += r1.y; o[6] += r1.z; o[7] += r1.w;
                }
                if constexpr (RES == 2) {
                    const u16* rp = (const u16*)res + (size_t)grow * ldres + gcol;
                    uint4 rv = *(const uint4*)rp;
                    o[0] += bf2f(rv.x & 0xffffu); o[1] += bf2f(rv.x >> 16);
                    o[2] += bf2f(rv.y & 0xffffu); o[3] += bf2f(rv.y >> 16);
                    o[4] += bf2f(rv.z & 0xffffu); o[5] += bf2f(rv.z >> 16);
                    o[6] += bf2f(rv.w & 0xffffu); o[7] += bf2f(rv.w >> 16);
                }
                if constexpr (RES == 3) {
                    const u16* rp = (const u16*)res + (size_t)grow * ldres + gcol;
                    uint4 rv = *(const uint4*)rp;
                    float hv[8] = {
                        bf2f(rv.x & 0xffffu), bf2f(rv.x >> 16),
                        bf2f(rv.y & 0xffffu), bf2f(rv.y >> 16),
                        bf2f(rv.z & 0xffffu), bf2f(rv.z >> 16),
                        bf2f(rv.w & 0xffffu), bf2f(rv.w >> 16)};
                    #pragma unroll
                    for (int q = 0; q < 2; ++q) {
                        float4 av = *(const float4*)&abp[gcol + q * 4];
                        float4 cv = *(const float4*)&abp[128 + gcol + q * 4];
                        o[q * 4]     += av.x * hv[q * 4]     + cv.x;
                        o[q * 4 + 1] += av.y * hv[q * 4 + 1] + cv.y;
                        o[q * 4 + 2] += av.z * hv[q * 4 + 2] + cv.z;
                        o[q * 4 + 3] += av.w * hv[q * 4 + 3] + cv.w;
                    }
                }
                if constexpr (RELU) {
                    #pragma unroll
                    for (int r = 0; r < 8; ++r) o[r] = fmaxf(o[r], 0.f);
                }
                if constexpr (STATS) {
                    #pragma unroll
                    for (int r = 0; r < 8; ++r) { ss[r] += o[r]; sq[r] += o[r] * o[r]; }
                }
                if constexpr (OUT16) {
                    uint4 pk;
                    pk.x = (unsigned)f2b(o[0]) | ((unsigned)f2b(o[1]) << 16);
                    pk.y = (unsigned)f2b(o[2]) | ((unsigned)f2b(o[3]) << 16);
                    pk.z = (unsigned)f2b(o[4]) | ((unsigned)f2b(o[5]) << 16);
                    pk.w = (unsigned)f2b(o[6]) | ((unsigned)f2b(o[7]) << 16);
                    *(uint4*)&((u16*)Cout)[(size_t)grow * ldc + gcol] = pk;
                } else {
                    float* cp = (float*)Cout + (size_t)grow * ldc + gcol;
                    *(float4*)cp = make_float4(o[0], o[1], o[2], o[3]);
                    *(float4*)(cp + 4) = make_float4(o[4], o[5], o[6], o[7]);
                }
            }
        }
        __syncthreads();
    }

    if constexpr (STATS) {
        #pragma unroll
        for (int r = 0; r < 8; ++r) {
            ss[r] += __shfl_xor(ss[r], 16); ss[r] += __shfl_xor(ss[r], 32);
            sq[r] += __shfl_xor(sq[r], 16); sq[r] += __shfl_xor(sq[r], 32);
        }
        if (lane < 16) {
            #pragma unroll
            for (int r = 0; r < 8; ++r) {
                stbuf[wave][lane][r] = ss[r];
                stbuf[wave][lane][8 + r] = sq[r];
            }
        }
        __syncthreads();
        int c16 = tid >> 4, r = tid & 15;
        float v = stbuf[0][c16][r] + stbuf[1][c16][r] + stbuf[2][c16][r] + stbuf[3][c16][r];
        int col = bn + c16 * 8 + (r & 7);
        atomicAdd(&stats[(r < 8 ? 0 : 128) + col], v);
    }
}

// ---------------- attention: 16-lane group per dst node (r1-proven structure) ----
// Fixed-capacity rows: beg = n*CAP, deg = cur[n]; overflow side-list handled at
// the end (empty in practice). No running max (|score| <~ 3 => exp safe in fp32).
// qkvs row layout: [q(128)|k(128)|v(128)|t_init(128)] bf16, stride 512 (1024 B).

__global__ __launch_bounds__(256) void attn_kernel(
    const u16* __restrict__ qkvs, const int* __restrict__ deg_arr,
    const int* __restrict__ colA, const int* __restrict__ ovcnt,
    const int* __restrict__ ov, u16* __restrict__ t16, int Nn)
{
    int tid = threadIdx.x;
    int gid = tid >> 4;              // group in block, 0..15
    int gl = tid & 15;               // lane in group
    int n = blockIdx.x * 16 + gid;
    if (n >= Nn) return;

    int deg = deg_arr[n];
    int beg = n * CAP;
    int end = beg + (deg < CAP ? deg : CAP);
    const char* base = (const char*)qkvs;
    const u16* qr = qkvs + (size_t)n * 512;
    uint4 qu = *(const uint4*)(qr + gl * 8);
    float q[8] = { blo(qu.x), bhi(qu.x), blo(qu.y), bhi(qu.y),
                   blo(qu.z), bhi(qu.z), blo(qu.w), bhi(qu.w) };

    const float scale = 0.08838834764831845f;   // 1/sqrt(128)
    float l = 0.f;
    float a[8] = {0.f, 0.f, 0.f, 0.f, 0.f, 0.f, 0.f, 0.f};
    unsigned lbyte = (unsigned)gl * 16u;        // byte offset within 256B chunk

#define ATTN_DOT(kk_, d_)                                              \
    {                                                                  \
        d_  = q[0] * blo(kk_.x); d_ = fmaf(q[1], bhi(kk_.x), d_);      \
        d_ = fmaf(q[2], blo(kk_.y), d_); d_ = fmaf(q[3], bhi(kk_.y), d_);\
        d_ = fmaf(q[4], blo(kk_.z), d_); d_ = fmaf(q[5], bhi(kk_.z), d_);\
        d_ = fmaf(q[6], blo(kk_.w), d_); d_ = fmaf(q[7], bhi(kk_.w), d_);\
    }
#define ATTN_UPD(dd_, vv_)                                             \
    {                                                                  \
        float d_ = dd_;                                                \
        d_ += __shfl_xor(d_, 1); d_ += __shfl_xor(d_, 2);              \
        d_ += __shfl_xor(d_, 4); d_ += __shfl_xor(d_, 8);              \
        float p_ = __expf(d_ * scale);                                 \
        l += p_;                                                       \
        a[0] = fmaf(p_, blo(vv_.x), a[0]); a[1] = fmaf(p_, bhi(vv_.x), a[1]);\
        a[2] = fmaf(p_, blo(vv_.y), a[2]); a[3] = fmaf(p_, bhi(vv_.y), a[3]);\
        a[4] = fmaf(p_, blo(vv_.z), a[4]); a[5] = fmaf(p_, bhi(vv_.z), a[5]);\
        a[6] = fmaf(p_, blo(vv_.w), a[6]); a[7] = fmaf(p_, bhi(vv_.w), a[7]);\
    }

    int i = beg;
    for (; i + 8 <= end; i += 8) {
        uint4 kk[8], vv[8];
        #pragma unroll
        for (int u = 0; u < 8; ++u) {
            unsigned off = ((unsigned)colA[i + u] << 10) + lbyte;
            kk[u] = *(const uint4*)(base + off + 256);
            vv[u] = *(const uint4*)(base + off + 512);
        }
        #pragma unroll
        for (int u = 0; u < 8; ++u) {
            float d; ATTN_DOT(kk[u], d);
            ATTN_UPD(d, vv[u]);
        }
    }
    for (; i + 4 <= end; i += 4) {
        uint4 kk[4], vv[4];
        #pragma unroll
        for (int u = 0; u < 4; ++u) {
            unsigned off = ((unsigned)colA[i + u] << 10) + lbyte;
            kk[u] = *(const uint4*)(base + off + 256);
            vv[u] = *(const uint4*)(base + off + 512);
        }
        #pragma unroll
        for (int u = 0; u < 4; ++u) {
            float d; ATTN_DOT(kk[u], d);
            ATTN_UPD(d, vv[u]);
        }
    }
    for (; i < end; ++i) {
        unsigned off = ((unsigned)colA[i] << 10) + lbyte;
        uint4 kk = *(const uint4*)(base + off + 256);
        uint4 vv = *(const uint4*)(base + off + 512);
        float d; ATTN_DOT(kk, d);
        ATTN_UPD(d, vv);
    }
    // overflow edges (deg > CAP); empty for this data, correctness path only
    int ovn = *ovcnt;
    if (ovn > 0) {
        if (ovn > OVCAP) ovn = OVCAP;
        for (int j = 0; j < ovn; ++j) {
            if (ov[2 * j] == n) {
                unsigned off = ((unsigned)ov[2 * j + 1] << 10) + lbyte;
                uint4 kk = *(const uint4*)(base + off + 256);
                uint4 vv = *(const uint4*)(base + off + 512);
                float d; ATTN_DOT(kk, d);
                ATTN_UPD(d, vv);
            }
        }
    }
#undef ATTN_DOT
#undef ATTN_UPD

    uint4 tu = *(const uint4*)(qr + 384 + gl * 8);
    float t[8] = { blo(tu.x), bhi(tu.x), blo(tu.y), bhi(tu.y),
                   blo(tu.z), bhi(tu.z), blo(tu.w), bhi(tu.w) };
    if (l > 0.f) {
        float inv = 1.f / l;
        #pragma unroll
        for (int c = 0; c < 8; ++c) t[c] = fmaf(a[c], inv, t[c]);
    }
    uint4 pk;
    pk.x = (unsigned)f2b(t[0]) | ((unsigned)f2b(t[1]) << 16);
    pk.y = (unsigned)f2b(t[2]) | ((unsigned)f2b(t[3]) << 16);
    pk.z = (unsigned)f2b(t[4]) | ((unsigned)f2b(t[5]) << 16);
    pk.w = (unsigned)f2b(t[6]) | ((unsigned)f2b(t[7]) << 16);
    *(uint4*)&t16[(size_t)n * 128 + gl * 8] = pk;
}

// ---------------- BN2 apply (prep fused; reads bf16 h2) ----------------
// Each thread handles 8 bf16 (uint4) -> writes 2x float4 (32B) coalesced.

__global__ __launch_bounds__(256) void bn_apply_kernel(
    const u16* __restrict__ h, const float* __restrict__ stats,
    const float* __restrict__ g, const float* __restrict__ be,
    float* __restrict__ out, int total8, float invN)
{
    __shared__ float ab[256];
    int tid = threadIdx.x;
    if (tid < 128) {
        float mean = stats[tid] * invN;
        float var = stats[128 + tid] * invN - mean * mean;
        float a = g[tid] * rsqrtf(var + EPS);
        ab[tid] = a;
        ab[128 + tid] = be[tid] - a * mean;
    }
    __syncthreads();
    int stride = gridDim.x * 256;
    for (int i8 = blockIdx.x * 256 + tid; i8 < total8; i8 += stride) {
        int cb = (i8 & 15) * 8;
        uint4 hv = ((const uint4*)h)[i8];
        float o[8] = { blo(hv.x), bhi(hv.x), blo(hv.y), bhi(hv.y),
                       blo(hv.z), bhi(hv.z), blo(hv.w), bhi(hv.w) };
        float* cp = out + (size_t)i8 * 8;
        *(float4*)cp = make_float4(
            ab[cb] * o[0] + ab[128 + cb],
            ab[cb + 1] * o[1] + ab[128 + cb + 1],
            ab[cb + 2] * o[2] + ab[128 + cb + 2],
            ab[cb + 3] * o[3] + ab[128 + cb + 3]);
        *(float4*)(cp + 4) = make_float4(
            ab[cb + 4] * o[4] + ab[128 + cb + 4],
            ab[cb + 5] * o[5] + ab[128 + cb + 5],
            ab[cb + 6] * o[6] + ab[128 + cb + 6],
            ab[cb + 7] * o[7] + ab[128 + cb + 7]);
    }
}

// ---------------- launch ----------------

extern "C" void kernel_launch(void* const* d_in, const int* in_sizes, int n_in,
                              void* d_out, int out_size, void* d_ws, size_t ws_size,
                              hipStream_t stream) {
    const float* x  = (const float*)d_in[0];
    const int*   ei = (const int*)d_in[1];
    const float* Wq = (const float*)d_in[2];  const float* bq = (const float*)d_in[3];
    const float* Wk = (const float*)d_in[4];  const float* bk = (const float*)d_in[5];
    const float* Wv = (const float*)d_in[6];  const float* bv = (const float*)d_in[7];
    const float* Ws = (const float*)d_in[8];  const float* bs = (const float*)d_in[9];
    const float* WO = (const float*)d_in[10]; const float* bO = (const float*)d_in[11];
    const float* W1 = (const float*)d_in[12]; const float* b1 = (const float*)d_in[13];
    const float* W2 = (const float*)d_in[14]; const float* b2 = (const float*)d_in[15];
    const float* g1 = (const float*)d_in[16]; const float* be1 = (const float*)d_in[17];
    const float* g2 = (const float*)d_in[18]; const float* be2 = (const float*)d_in[19];

    const int N = in_sizes[0] / D;            // 50000
    const int E = in_sizes[1] / 2;            // 800000
    float* out = (float*)d_out;

    int gm = (N + GBM - 1) / GBM;             // 391
    int Npad = gm * GBM;                      // 50048
    size_t NDp = (size_t)Npad * D;

    // ---- workspace (~88 MB) ----
    u16* buf0 = (u16*)d_ws;                   // [Npad][128]: x16 -> h16 (in-place at Oproj)
    u16* t16 = buf0 + NDp;                    // [Npad][128] attn output
    u16* qkvs = t16 + NDp;                    // [Npad][512]
    float* stats = (float*)(qkvs + (size_t)Npad * 512);  // 512 (BN1 | BN2)
    float* ab1 = stats + 512;                 // 256
    float* bqkvs = ab1 + 256;                 // 512
    float* b1p = bqkvs + 512;                 // 256
    u16* wt = (u16*)(b1p + 256);              // 147456: Wqkvs|WO|W2|W1'
    int* cur = (int*)(wt + 147456);           // N   (memset N+1 covers ovcnt)
    int* ovcnt = cur + N;                     // 1
    int* ov = ovcnt + 1;                      // 2*OVCAP
    int* colA = ov + 2 * OVCAP;               // CAP*N
    // aliases:
    u16* x16 = buf0;                          // pad rows zeroed by setup
    u16* h16 = buf0;                          // Oproj writes in-place (row-owned, RES=2 from x16)
    u16* zb16 = qkvs;                         // [Npad][256]; qkvs dead after attn
    u16* h2b = qkvs + (size_t)Npad * 256;     // [N][128] bf16 pre-BN2, disjoint from zb16

    // --- setup (x16 + biases + zeros + weight prep) ---
    hipMemsetAsync(cur, 0, (size_t)(N + 1) * sizeof(int), stream);
    setup_kernel<<<1136, 256, 0, stream>>>(x, x16, bq, bk, bv, bs, bqkvs, stats, b1p,
                                           Wq, Wk, Wv, Ws, WO, W2, wt,
                                           N * 32, Npad * 32);

    // --- edge-fill slice (y=0, launches first) + QKVS GEMM (y=1..4), one dispatch ---
    gemm_k<0, true, false, false, true><<<dim3(gm, 5), 256, 0, stream>>>(
        x16, wt, bqkvs, nullptr, 0, nullptr, qkvs, 512, nullptr, Npad, 128,
        ei, cur, colA, ovcnt, ov, E);

    // --- attention: t16 = t_init + softmax-agg(v) ---
    attn_kernel<<<(N + 15) / 16, 256, 0, stream>>>(qkvs, cur, colA, ovcnt, ov, t16, N);

    // --- O-proj + residual1(bf16 x16) + BN1 stats: h16 = bf16(x16 + t16@WO + bO) ---
    gemm_k<2, true, true, false, false><<<dim3(gm, 1), 256, 0, stream>>>(
        t16, wt + 65536, bO, x16, 128, nullptr, h16, 128, stats, N, 128,
        nullptr, nullptr, nullptr, nullptr, nullptr, 0);

    // --- prep1 (parallel): ab1, W1' (bf16, BN1 folded), b1' ---
    prep1_kernel<<<8, 256, 0, stream>>>(stats, g1, be1, W1, b1, ab1, wt + 114688, b1p,
                                        1.f / (float)N);

    // --- FFN1: zb16 = relu(h16@W1' + b1'), all Npad rows (pads -> relu(b1'), defined) ---
    gemm_k<0, true, false, true, false><<<dim3(gm, 2), 256, 0, stream>>>(
        h16, wt + 114688, b1p, nullptr, 0, nullptr, zb16, 256, nullptr, Npad, 128,
        nullptr, nullptr, nullptr, nullptr, nullptr, 0);

    // --- FFN2 + residual2(bn1) + BN2 stats: h2b = bf16((a1*h16+c1) + zb16@W2 + b2) ---
    gemm_k<3, true, true, false, false><<<dim3(gm, 1), 256, 0, stream>>>(
        zb16, wt + 81920, b2, h16, 128, ab1, h2b, 128, stats + 256, N, 256,
        nullptr, nullptr, nullptr, nullptr, nullptr, 0);

    // --- BN2 apply (prep fused) -> out ---
    bn_apply_kernel<<<1024, 256, 0, stream>>>(h2b, stats + 256, g2, be2, out,
                                              N * 16, 1.f / (float)N);
}